// Round 1
// baseline (184.154 us; speedup 1.0000x reference)
//
#include <hip/hip_runtime.h>

#define NEG_INF (-3.402823466e+38f)

typedef __attribute__((ext_vector_type(8))) short bf16x8;
typedef __attribute__((ext_vector_type(4))) float f32x4;

__device__ __forceinline__ unsigned short f2bf(float f) {
  union { float f; unsigned u; } v; v.f = f;
  unsigned r = v.u + 0x7fffu + ((v.u >> 16) & 1u);
  return (unsigned short)(r >> 16);
}
__device__ __forceinline__ float bf2f(unsigned short h) {
  union { unsigned u; float f; } v; v.u = ((unsigned)h) << 16; return v.f;
}

__device__ __forceinline__ bf16x8 pack_bf8(const float* __restrict__ p) {
  float4 a = *(const float4*)p;
  float4 b = *(const float4*)(p + 4);
  bf16x8 r;
  r[0] = (short)f2bf(a.x); r[1] = (short)f2bf(a.y);
  r[2] = (short)f2bf(a.z); r[3] = (short)f2bf(a.w);
  r[4] = (short)f2bf(b.x); r[5] = (short)f2bf(b.y);
  r[6] = (short)f2bf(b.z); r[7] = (short)f2bf(b.w);
  return r;
}

// Convert the four 128x128 fp32 weight matrices to bf16 in workspace.
__global__ __launch_bounds__(256) void cvt_weights(
    const float* __restrict__ wq, const float* __restrict__ wk,
    const float* __restrict__ wv, const float* __restrict__ wo,
    unsigned short* __restrict__ q, unsigned short* __restrict__ k,
    unsigned short* __restrict__ v, unsigned short* __restrict__ o) {
  int i = blockIdx.x * 256 + threadIdx.x;
  if (i < 128 * 128) {
    q[i] = f2bf(wq[i]);
    k[i] = f2bf(wk[i]);
    v[i] = f2bf(wv[i]);
    o[i] = f2bf(wo[i]);
  }
}

// Y[M][128] = X[M][128] @ W^T, W given as bf16 [o][i] (o-major, 128x128).
// Block: 256 threads = 4 waves, 64 rows per block (16 rows per wave).
__global__ __launch_bounds__(256) void gemm_xwt(
    const float* __restrict__ X, const unsigned short* __restrict__ Wbf,
    float* __restrict__ Y, int M) {
  __shared__ unsigned short Wl[128 * 136];
  for (int idx = threadIdx.x; idx < 128 * 128; idx += 256)
    Wl[(idx >> 7) * 136 + (idx & 127)] = Wbf[idx];
  __syncthreads();

  const int wave = threadIdx.x >> 6, lane = threadIdx.x & 63;
  const int lr = lane & 15, lk = lane >> 4;
  const int row0 = blockIdx.x * 64 + wave * 16;
  const int arow = row0 + lr;

  bf16x8 af[4];
  if (arow < M) {
    const float* xr = X + (size_t)arow * 128;
#pragma unroll
    for (int kk = 0; kk < 4; ++kk) af[kk] = pack_bf8(xr + kk * 32 + lk * 8);
  } else {
#pragma unroll
    for (int kk = 0; kk < 4; ++kk) af[kk] = (bf16x8)(short)0;
  }

  f32x4 acc[8];
#pragma unroll
  for (int ct = 0; ct < 8; ++ct) acc[ct] = (f32x4){0.f, 0.f, 0.f, 0.f};

#pragma unroll
  for (int kk = 0; kk < 4; ++kk) {
#pragma unroll
    for (int ct = 0; ct < 8; ++ct) {
      bf16x8 b = *(const bf16x8*)&Wl[(ct * 16 + lr) * 136 + kk * 32 + lk * 8];
      acc[ct] = __builtin_amdgcn_mfma_f32_16x16x32_bf16(af[kk], b, acc[ct], 0, 0, 0);
    }
  }

#pragma unroll
  for (int ct = 0; ct < 8; ++ct) {
#pragma unroll
    for (int r = 0; r < 4; ++r) {
      int row = row0 + lk * 4 + r;
      if (row < M) Y[(size_t)row * 128 + ct * 16 + lr] = acc[ct][r];
    }
  }
}

// Fused neighbor attention. One wave per node; 8 waves (512 thr) per block;
// 4 node-iterations per wave => 32 nodes per block.
// attOut[n][h*32+d] = sum_k attend[n,h,k] * V[n,k,h,d]
__global__ __launch_bounds__(512) void neigh_attn(
    const float* __restrict__ hE, const int* __restrict__ mask,
    const unsigned short* __restrict__ WkBf, const unsigned short* __restrict__ WvBf,
    const float* __restrict__ Qg, float* __restrict__ attOut, int N) {
  __shared__ unsigned short Wk[128 * 136];
  __shared__ unsigned short Wv[128 * 136];
  __shared__ unsigned short KV[8][32 * 136];
  __shared__ float Qs[8][128];
  __shared__ float Att[8][4][32];

  for (int idx = threadIdx.x; idx < 128 * 128; idx += 512) {
    int d = (idx >> 7) * 136 + (idx & 127);
    Wk[d] = WkBf[idx];
    Wv[d] = WvBf[idx];
  }
  __syncthreads();

  const int wave = threadIdx.x >> 6, lane = threadIdx.x & 63;
  const int lr = lane & 15, lk = lane >> 4;
  unsigned short* kv = KV[wave];
  float* qs = Qs[wave];
  float(*att)[32] = Att[wave];

  for (int it = 0; it < 4; ++it) {
    int n = blockIdx.x * 32 + it * 8 + wave;
    if (n >= N) break;
    const float* E = hE + (size_t)n * 4096;

    // stage Q row (128 floats) for broadcast reads
    qs[lane] = Qg[(size_t)n * 128 + lane];
    qs[lane + 64] = Qg[(size_t)n * 128 + lane + 64];

    // load the 32x128 h_E tile as bf16 A-fragments (whole tile, once)
    bf16x8 af[2][4];
#pragma unroll
    for (int rt = 0; rt < 2; ++rt)
#pragma unroll
      for (int kk = 0; kk < 4; ++kk)
        af[rt][kk] = pack_bf8(E + (rt * 16 + lr) * 128 + kk * 32 + lk * 8);

    // ---- K projection: K[k][o] = sum_i E[k][i] * Wk[o][i] ----
#pragma unroll
    for (int rt = 0; rt < 2; ++rt) {
#pragma unroll
      for (int ct = 0; ct < 8; ++ct) {
        f32x4 acc = {0.f, 0.f, 0.f, 0.f};
#pragma unroll
        for (int kk = 0; kk < 4; ++kk) {
          bf16x8 b = *(const bf16x8*)&Wk[(ct * 16 + lr) * 136 + kk * 32 + lk * 8];
          acc = __builtin_amdgcn_mfma_f32_16x16x32_bf16(af[rt][kk], b, acc, 0, 0, 0);
        }
#pragma unroll
        for (int r = 0; r < 4; ++r)
          kv[(rt * 16 + lk * 4 + r) * 136 + ct * 16 + lr] = f2bf(acc[r]);
      }
    }

    // ---- logits + masked softmax (k = lane&31; each lane covers 2 heads) ----
    const int k = lane & 31, hp = lane >> 5;
    const float mflt = (float)mask[(size_t)n * 32 + k];
#pragma unroll
    for (int hh = 0; hh < 2; ++hh) {
      const int h = hp + 2 * hh;
      float s = 0.f;
      const unsigned short* krow = &kv[k * 136 + h * 32];
#pragma unroll
      for (int d = 0; d < 32; ++d) s += qs[h * 32 + d] * bf2f(krow[d]);
      s *= 0.17677669529663689f;  // 1/sqrt(32)
      float logit = (mflt > 0.f) ? s : NEG_INF;
      float mx = logit;
#pragma unroll
      for (int off = 16; off >= 1; off >>= 1) mx = fmaxf(mx, __shfl_xor(mx, off, 64));
      float e = __expf(logit - mx);
      float sum = e;
#pragma unroll
      for (int off = 16; off >= 1; off >>= 1) sum += __shfl_xor(sum, off, 64);
      att[h][k] = e / sum * mflt;
    }

    // ---- V projection into the same buffer (DS ops are in-order per wave) ----
#pragma unroll
    for (int rt = 0; rt < 2; ++rt) {
#pragma unroll
      for (int ct = 0; ct < 8; ++ct) {
        f32x4 acc = {0.f, 0.f, 0.f, 0.f};
#pragma unroll
        for (int kk = 0; kk < 4; ++kk) {
          bf16x8 b = *(const bf16x8*)&Wv[(ct * 16 + lr) * 136 + kk * 32 + lk * 8];
          acc = __builtin_amdgcn_mfma_f32_16x16x32_bf16(af[rt][kk], b, acc, 0, 0, 0);
        }
#pragma unroll
        for (int r = 0; r < 4; ++r)
          kv[(rt * 16 + lk * 4 + r) * 136 + ct * 16 + lr] = f2bf(acc[r]);
      }
    }

    // ---- PV: out[o] = sum_k att[o>>5][k] * V[k][o] ----
#pragma unroll
    for (int half = 0; half < 2; ++half) {
      int o = lane + 64 * half;
      int h = o >> 5;
      float r = 0.f;
#pragma unroll
      for (int k2 = 0; k2 < 32; ++k2) r += att[h][k2] * bf2f(kv[k2 * 136 + o]);
      attOut[(size_t)n * 128 + o] = r;
    }
  }
}

extern "C" void kernel_launch(void* const* d_in, const int* in_sizes, int n_in,
                              void* d_out, int out_size, void* d_ws, size_t ws_size,
                              hipStream_t stream) {
  const float* hV = (const float*)d_in[0];
  const float* hE = (const float*)d_in[1];
  const int* mask = (const int*)d_in[2];
  const float* Wq = (const float*)d_in[3];
  const float* Wk = (const float*)d_in[4];
  const float* Wv = (const float*)d_in[5];
  const float* Wo = (const float*)d_in[6];
  float* out = (float*)d_out;
  const int N = in_sizes[0] / 128;  // 30000

  char* ws = (char*)d_ws;
  unsigned short* wqb = (unsigned short*)(ws);
  unsigned short* wkb = (unsigned short*)(ws + 32768);
  unsigned short* wvb = (unsigned short*)(ws + 65536);
  unsigned short* wob = (unsigned short*)(ws + 98304);
  float* Qbuf = (float*)(ws + 131072);
  float* Abuf = (float*)(ws + 131072 + (size_t)N * 128 * 4);

  cvt_weights<<<64, 256, 0, stream>>>(Wq, Wk, Wv, Wo, wqb, wkb, wvb, wob);
  gemm_xwt<<<(N + 63) / 64, 256, 0, stream>>>(hV, wqb, Qbuf, N);
  neigh_attn<<<(N + 31) / 32, 512, 0, stream>>>(hE, mask, wkb, wvb, Qbuf, Abuf, N);
  gemm_xwt<<<(N + 63) / 64, 256, 0, stream>>>(Abuf, wob, out, N);
}